// Round 1
// baseline (136.750 us; speedup 1.0000x reference)
//
#include <hip/hip_runtime.h>

// Problem constants (from setup_inputs): B=16, C=16, H=W=512, cell=16x16.
#define BATCH 16
#define CHAN  16
#define HDIM  512
#define WDIM  512
#define H_CELL 16
#define W_CELL 16
#define HH (HDIM / H_CELL)   // 32
#define WW (WDIM / W_CELL)   // 32

__global__ __launch_bounds__(256) void p2sp_kernel(
    const float* __restrict__ x,          // [B, C, H, W]
    const float* __restrict__ st,         // [B, C, HH, WW]
    const float* __restrict__ para,       // [1, 1, 256, 9]
    float* __restrict__ out)              // [B, 9, H, W]
{
    const int cell = blockIdx.x;          // 0 .. HH*WW-1
    const int b    = blockIdx.y;          // 0 .. B-1
    const int ic   = cell / WW;
    const int jc   = cell % WW;

    const int tid = threadIdx.x;          // 0..255 = pixel index p = pi*16+pj
    const int pi  = tid >> 4;
    const int pj  = tid & 15;

    // Stoken fragments for the 3x3 neighborhood: sf[c][k], k = di*3+dj
    __shared__ float sf[CHAN][9];

    if (tid < CHAN * 9) {
        const int c  = tid / 9;
        const int k  = tid % 9;
        const int ni = ic + (k / 3) - 1;
        const int nj = jc + (k % 3) - 1;
        float v = 0.0f;
        if (ni >= 0 && ni < HH && nj >= 0 && nj < WW) {
            v = st[(((size_t)b * CHAN + c) * HH + ni) * WW + nj];
        }
        sf[c][k] = v;
    }
    __syncthreads();

    const int gi = ic * H_CELL + pi;      // global row
    const int gj = jc * W_CELL + pj;      // global col

    float acc[9];
    #pragma unroll
    for (int k = 0; k < 9; ++k) acc[k] = 0.0f;

    const float* xp = x + (((size_t)b * CHAN) * HDIM + gi) * WDIM + gj;
    #pragma unroll
    for (int c = 0; c < CHAN; ++c) {
        const float xv = xp[(size_t)c * HDIM * WDIM];
        #pragma unroll
        for (int k = 0; k < 9; ++k) acc[k] = fmaf(xv, sf[c][k], acc[k]);
    }

    const float scale = 0.25f;            // C^-0.5, C=16
    const float* pp = para + (size_t)tid * 9;
    float aff[9];
    float m = -INFINITY;
    #pragma unroll
    for (int k = 0; k < 9; ++k) {
        aff[k] = acc[k] * scale * pp[k];
        m = fmaxf(m, aff[k]);
    }
    float s = 0.0f;
    #pragma unroll
    for (int k = 0; k < 9; ++k) {
        aff[k] = __expf(aff[k] - m);
        s += aff[k];
    }
    const float inv = 1.0f / s;

    const size_t obase = (((size_t)b * 9) * HDIM + gi) * WDIM + gj;
    #pragma unroll
    for (int k = 0; k < 9; ++k) {
        out[obase + (size_t)k * HDIM * WDIM] = aff[k] * inv;
    }
}

extern "C" void kernel_launch(void* const* d_in, const int* in_sizes, int n_in,
                              void* d_out, int out_size, void* d_ws, size_t ws_size,
                              hipStream_t stream) {
    const float* x    = (const float*)d_in[0];
    const float* st   = (const float*)d_in[1];
    const float* para = (const float*)d_in[2];
    float* out        = (float*)d_out;

    dim3 grid(HH * WW, BATCH);
    dim3 block(256);
    p2sp_kernel<<<grid, block, 0, stream>>>(x, st, para, out);
}

// Round 2
// 70.460 us; speedup vs baseline: 1.9408x; 1.9408x over previous
//
#include <hip/hip_runtime.h>

// Problem constants: B=16, C=16, H=W=512, cell=16x16 -> 32x32 cells.
#define BATCH 16
#define CHAN  16
#define HDIM  512
#define WDIM  512
#define HH 32
#define WW 32

typedef float f32x4 __attribute__((ext_vector_type(4)));

// Block: 256 threads = 4 rows x 64 lanes; each lane processes 4 consecutive
// pixels (float4). Block tile = 4 rows x 256 cols, spanning 16 cells
// horizontally (all within one cell-row since 4 | 16).
// Grid: (W/256, H/4, B) = (2, 128, 16).

__global__ __launch_bounds__(256) void p2sp_kernel(
    const float* __restrict__ x,          // [B, C, H, W]
    const float* __restrict__ st,         // [B, C, HH, WW]
    const float* __restrict__ para,       // [1, 1, 256, 9]
    float* __restrict__ out)              // [B, 9, H, W]
{
    const int t    = threadIdx.x;
    const int lane = t & 63;
    const int wrow = t >> 6;                 // 0..3
    const int b    = blockIdx.z;
    const int gi   = blockIdx.y * 4 + wrow;  // global row
    const int gjb  = blockIdx.x * 256;       // block col base
    const int gj   = gjb + lane * 4;
    const int ic   = blockIdx.y >> 2;        // cell row (uniform over block)
    const int jc0  = gjb >> 4;               // first cell col of the block

    // Stoken fragments for 16 cells: [c][k][cell] — lanes read 16 consecutive
    // words per (c,k) with 4-lane broadcast -> conflict-free.
    __shared__ float sf[CHAN][9][16];
    // para * scale for the block's 4 rows: [wrow][pj][k]
    __shared__ float pp[4][16][9];

    // stage stoken fragments: 16*9*16 = 2304 elems, 9 per thread
    for (int idx = t; idx < CHAN * 9 * 16; idx += 256) {
        const int cc  = idx & 15;
        const int rem = idx >> 4;            // c*9 + k
        const int k   = rem % 9;
        const int c   = rem / 9;
        const int ni  = ic + k / 3 - 1;
        const int nj  = jc0 + cc + (k % 3) - 1;
        float v = 0.0f;
        if (ni >= 0 && ni < HH && nj >= 0 && nj < WW)
            v = st[(((size_t)b * CHAN + c) * HH + ni) * WW + nj];
        sf[c][k][cc] = v;
    }
    // stage para (pre-multiplied by C^-0.5 = 0.25): 4*16*9 = 576 elems
    {
        const int pi0 = (blockIdx.y * 4) & 15;
        for (int idx = t; idx < 4 * 16 * 9; idx += 256) {
            const int k  = idx % 9;
            const int r  = idx / 9;          // wr*16 + pj
            const int wr = r >> 4;
            const int pj = r & 15;
            const int p  = (pi0 + wr) * 16 + pj;
            pp[wr][pj][k] = para[p * 9 + k] * 0.25f;
        }
    }
    __syncthreads();

    const int cc  = lane >> 2;               // which of the 16 cells
    const int pjb = (lane & 3) * 4;          // pj of first owned pixel

    const float* xp = x + (((size_t)b * CHAN) * HDIM + gi) * WDIM + gj;

    float acc[4][9];
    #pragma unroll
    for (int k = 0; k < 9; ++k) {
        acc[0][k] = 0.f; acc[1][k] = 0.f; acc[2][k] = 0.f; acc[3][k] = 0.f;
    }

    #pragma unroll
    for (int c = 0; c < CHAN; ++c) {
        const f32x4 xv = *reinterpret_cast<const f32x4*>(xp + (size_t)c * (HDIM * WDIM));
        #pragma unroll
        for (int k = 0; k < 9; ++k) {
            const float w = sf[c][k][cc];
            acc[0][k] = fmaf(xv.x, w, acc[0][k]);
            acc[1][k] = fmaf(xv.y, w, acc[1][k]);
            acc[2][k] = fmaf(xv.z, w, acc[2][k]);
            acc[3][k] = fmaf(xv.w, w, acc[3][k]);
        }
    }

    // softmax per pixel, transpose into [k][q] for float4 stores
    float res[9][4];
    #pragma unroll
    for (int q = 0; q < 4; ++q) {
        float a[9];
        float m = -INFINITY;
        #pragma unroll
        for (int k = 0; k < 9; ++k) {
            a[k] = acc[q][k] * pp[wrow][pjb + q][k];
            m = fmaxf(m, a[k]);
        }
        float s = 0.f;
        #pragma unroll
        for (int k = 0; k < 9; ++k) { a[k] = __expf(a[k] - m); s += a[k]; }
        const float inv = 1.0f / s;
        #pragma unroll
        for (int k = 0; k < 9; ++k) res[k][q] = a[k] * inv;
    }

    float* op = out + (((size_t)b * 9) * HDIM + gi) * WDIM + gj;
    #pragma unroll
    for (int k = 0; k < 9; ++k) {
        f32x4 v;
        v.x = res[k][0]; v.y = res[k][1]; v.z = res[k][2]; v.w = res[k][3];
        __builtin_nontemporal_store(v, reinterpret_cast<f32x4*>(op + (size_t)k * (HDIM * WDIM)));
    }
}

extern "C" void kernel_launch(void* const* d_in, const int* in_sizes, int n_in,
                              void* d_out, int out_size, void* d_ws, size_t ws_size,
                              hipStream_t stream) {
    const float* x    = (const float*)d_in[0];
    const float* st   = (const float*)d_in[1];
    const float* para = (const float*)d_in[2];
    float* out        = (float*)d_out;

    dim3 grid(WDIM / 256, HDIM / 4, BATCH);
    dim3 block(256);
    p2sp_kernel<<<grid, block, 0, stream>>>(x, st, para, out);
}